// Round 1
// baseline (212.740 us; speedup 1.0000x reference)
//
#include <hip/hip_runtime.h>

typedef __bf16 bf16x8 __attribute__((ext_vector_type(8)));
typedef float f32x4 __attribute__((ext_vector_type(4)));

#define NB 4
#define NC 64
#define NN 4096

// ---------------------------------------------------------------------------
// Kernel 1: QKV projection.  x:[B,C,N] fp32, w_qkv:[3C,C], b_qkv:[3C]
// Outputs: Q,K as bf16 [B,N,C]  (row-contiguous for MFMA A/B frags)
//          V   as bf16 [B,C,N]  (channel-major so PV B-frag reads are contiguous)
// grid(16, B, 6): z selects {q,k,v} x {low32,high32} output channels.
// ---------------------------------------------------------------------------
__global__ __launch_bounds__(256) void qkv_kernel(
    const float* __restrict__ x, const float* __restrict__ wqkv,
    const float* __restrict__ bqkv,
    __bf16* __restrict__ Qg, __bf16* __restrict__ Kg, __bf16* __restrict__ Vg)
{
  const int b = blockIdx.y;
  const int z = blockIdx.z;
  const int tsel = z >> 1;          // 0=q, 1=k, 2=v
  const int obase = (z & 1) * 32;   // which 32 output channels
  const int n = blockIdx.x * 256 + threadIdx.x;

  __shared__ float wsh[32 * 64];
  __shared__ float bsh[32];
  for (int i = threadIdx.x; i < 32 * 64; i += 256)
    wsh[i] = wqkv[tsel * 4096 + obase * 64 + i];
  if (threadIdx.x < 32) bsh[threadIdx.x] = bqkv[tsel * 64 + obase + threadIdx.x];
  __syncthreads();

  float xv[64];
#pragma unroll
  for (int c = 0; c < 64; c++)
    xv[c] = x[((size_t)(b * 64 + c)) * NN + n];   // coalesced across lanes

#pragma unroll 1
  for (int o8 = 0; o8 < 32; o8 += 8) {
    float a[8];
#pragma unroll
    for (int j = 0; j < 8; j++) a[j] = bsh[o8 + j];
#pragma unroll
    for (int c4 = 0; c4 < 64; c4 += 4) {
#pragma unroll
      for (int j = 0; j < 8; j++) {
        const float4 wv = *(const float4*)&wsh[(o8 + j) * 64 + c4];
        a[j] = fmaf(wv.x, xv[c4 + 0], a[j]);
        a[j] = fmaf(wv.y, xv[c4 + 1], a[j]);
        a[j] = fmaf(wv.z, xv[c4 + 2], a[j]);
        a[j] = fmaf(wv.w, xv[c4 + 3], a[j]);
      }
    }
    if (tsel == 2) {
#pragma unroll
      for (int j = 0; j < 8; j++)
        Vg[((size_t)(b * 64 + obase + o8 + j)) * NN + n] = (__bf16)a[j];  // coalesced
    } else {
      bf16x8 pk;
#pragma unroll
      for (int j = 0; j < 8; j++) pk[j] = (__bf16)a[j];
      __bf16* base = (tsel == 0 ? Qg : Kg);
      *(bf16x8*)(base + ((size_t)(b * NN + n)) * 64 + obase + o8) = pk;
    }
  }
}

// ---------------------------------------------------------------------------
// Kernel 2: flash attention.  Q,K:[B,N,C] bf16, V:[B,C,N] bf16 -> AO:[B,N,C] f32
// grid(64, B), 256 threads = 4 waves; each wave owns 16 queries.
// Key tiles of 64; online softmax in log2 domain.
// LDS rows padded to 72 bf16 (144 B, 16B-aligned) -> <=2-way bank aliasing.
// ---------------------------------------------------------------------------
__global__ __launch_bounds__(256) void flash_kernel(
    const __bf16* __restrict__ Q, const __bf16* __restrict__ K,
    const __bf16* __restrict__ V, float* __restrict__ AO)
{
  const int b = blockIdx.y;
  const int tid = threadIdx.x;
  const int wave = tid >> 6;
  const int lane = tid & 63;
  const int quad = lane >> 4;
  const int l16 = lane & 15;

  __shared__ __bf16 Kt[64 * 72];      // [key][c], padded
  __shared__ __bf16 Vt[64 * 72];      // [c][key], padded
  __shared__ __bf16 Pt[4][16 * 72];   // per-wave P scratch [q][key], padded

  const int q0 = blockIdx.x * 64 + wave * 16;

  // Q fragments: A[m=l16][k=quad*8+j] for c 0..31 and 32..63
  const __bf16* qrow = Q + ((size_t)(b * NN + q0 + l16)) * 64;
  const bf16x8 qf0 = *(const bf16x8*)(qrow + quad * 8);
  const bf16x8 qf1 = *(const bf16x8*)(qrow + 32 + quad * 8);

  f32x4 acc[4];     // O accumulator, c-tiles of 16; row=quad*4+r, col=l16
#pragma unroll
  for (int ct = 0; ct < 4; ct++) acc[ct] = (f32x4){0.f, 0.f, 0.f, 0.f};
  float m[4], l[4];
#pragma unroll
  for (int r = 0; r < 4; r++) { m[r] = -1e30f; l[r] = 0.f; }

  const float sc = 0.125f * 1.44269504088896340736f;  // 1/sqrt(C) * log2(e)

  for (int kt0 = 0; kt0 < NN; kt0 += 64) {
    __syncthreads();
    // stage K tile [64 keys][64 c] and V^T tile [64 c][64 keys]
#pragma unroll
    for (int it = 0; it < 2; it++) {
      const int chunk = tid + it * 256;          // 512 chunks of 8 bf16
      const int row = chunk >> 3, col8 = (chunk & 7) * 8;
      *(bf16x8*)(&Kt[row * 72 + col8]) =
          *(const bf16x8*)(K + ((size_t)(b * NN + kt0 + row)) * 64 + col8);
      *(bf16x8*)(&Vt[row * 72 + col8]) =
          *(const bf16x8*)(V + ((size_t)(b * 64 + row)) * NN + kt0 + col8);
    }
    __syncthreads();

    // S = Q K^T for 4 key tiles of 16
    f32x4 s[4];
#pragma unroll
    for (int t = 0; t < 4; t++) {
      const bf16x8 kf0 = *(const bf16x8*)(&Kt[(t * 16 + l16) * 72 + quad * 8]);
      const bf16x8 kf1 = *(const bf16x8*)(&Kt[(t * 16 + l16) * 72 + 32 + quad * 8]);
      f32x4 z = (f32x4){0.f, 0.f, 0.f, 0.f};
      z = __builtin_amdgcn_mfma_f32_16x16x32_bf16(qf0, kf0, z, 0, 0, 0);
      z = __builtin_amdgcn_mfma_f32_16x16x32_bf16(qf1, kf1, z, 0, 0, 0);
      s[t] = z;
    }

    // online softmax per row r (row = quad*4+r, cols distributed over 16 lanes)
    float alpha[4];
#pragma unroll
    for (int r = 0; r < 4; r++) {
      float s0 = s[0][r] * sc, s1 = s[1][r] * sc, s2 = s[2][r] * sc, s3 = s[3][r] * sc;
      float mx = fmaxf(fmaxf(s0, s1), fmaxf(s2, s3));
      mx = fmaxf(mx, __shfl_xor(mx, 1));
      mx = fmaxf(mx, __shfl_xor(mx, 2));
      mx = fmaxf(mx, __shfl_xor(mx, 4));
      mx = fmaxf(mx, __shfl_xor(mx, 8));
      const float mnew = fmaxf(m[r], mx);
      alpha[r] = exp2f(m[r] - mnew);
      m[r] = mnew;
      const float p0 = exp2f(s0 - mnew), p1 = exp2f(s1 - mnew);
      const float p2 = exp2f(s2 - mnew), p3 = exp2f(s3 - mnew);
      float rs = (p0 + p1) + (p2 + p3);
      rs += __shfl_xor(rs, 1);
      rs += __shfl_xor(rs, 2);
      rs += __shfl_xor(rs, 4);
      rs += __shfl_xor(rs, 8);
      l[r] = l[r] * alpha[r] + rs;
      // write P (bf16) to per-wave LDS: row=quad*4+r, col=t*16+l16
      Pt[wave][(quad * 4 + r) * 72 + 0 * 16 + l16] = (__bf16)p0;
      Pt[wave][(quad * 4 + r) * 72 + 1 * 16 + l16] = (__bf16)p1;
      Pt[wave][(quad * 4 + r) * 72 + 2 * 16 + l16] = (__bf16)p2;
      Pt[wave][(quad * 4 + r) * 72 + 3 * 16 + l16] = (__bf16)p3;
    }

    // rescale O accumulators
#pragma unroll
    for (int ct = 0; ct < 4; ct++)
#pragma unroll
      for (int r = 0; r < 4; r++) acc[ct][r] *= alpha[r];

    // O += P V : A[m=q=l16][k=key=quad*8+j] from Pt; B[k=key][n=c=l16] from Vt
#pragma unroll
    for (int kb = 0; kb < 2; kb++) {
      const bf16x8 pf = *(const bf16x8*)(&Pt[wave][l16 * 72 + kb * 32 + quad * 8]);
#pragma unroll
      for (int ct = 0; ct < 4; ct++) {
        const bf16x8 vf = *(const bf16x8*)(&Vt[(ct * 16 + l16) * 72 + kb * 32 + quad * 8]);
        acc[ct] = __builtin_amdgcn_mfma_f32_16x16x32_bf16(pf, vf, acc[ct], 0, 0, 0);
      }
    }
  }

  // epilogue: O /= l, store AO[B,N,C] fp32
#pragma unroll
  for (int ct = 0; ct < 4; ct++) {
#pragma unroll
    for (int r = 0; r < 4; r++) {
      const float o = acc[ct][r] / l[r];
      AO[((size_t)(b * NN + q0 + quad * 4 + r)) * 64 + ct * 16 + l16] = o;
    }
  }
}

// ---------------------------------------------------------------------------
// Kernel 3: output projection + bias + residual (fp32).
// AO:[B,N,C] f32, w_proj:[C,C], b_proj:[C], x:[B,C,N] -> out:[B,C,N] f32
// grid(16, B, 2): z selects 32 output channels.
// ---------------------------------------------------------------------------
__global__ __launch_bounds__(256) void proj_kernel(
    const float* __restrict__ AO, const float* __restrict__ wproj,
    const float* __restrict__ bproj, const float* __restrict__ x,
    float* __restrict__ out)
{
  const int b = blockIdx.y;
  const int obase = blockIdx.z * 32;
  const int n = blockIdx.x * 256 + threadIdx.x;

  __shared__ float wsh[32 * 64];
  __shared__ float bsh[32];
  for (int i = threadIdx.x; i < 32 * 64; i += 256) wsh[i] = wproj[obase * 64 + i];
  if (threadIdx.x < 32) bsh[threadIdx.x] = bproj[obase + threadIdx.x];
  __syncthreads();

  float av[64];
#pragma unroll
  for (int c4 = 0; c4 < 64; c4 += 4) {
    const float4 t = *(const float4*)&AO[((size_t)(b * NN + n)) * 64 + c4];
    av[c4] = t.x; av[c4 + 1] = t.y; av[c4 + 2] = t.z; av[c4 + 3] = t.w;
  }

#pragma unroll 1
  for (int o8 = 0; o8 < 32; o8 += 8) {
    float a[8];
#pragma unroll
    for (int j = 0; j < 8; j++) a[j] = bsh[o8 + j];
#pragma unroll
    for (int c4 = 0; c4 < 64; c4 += 4) {
#pragma unroll
      for (int j = 0; j < 8; j++) {
        const float4 wv = *(const float4*)&wsh[(o8 + j) * 64 + c4];
        a[j] = fmaf(wv.x, av[c4 + 0], a[j]);
        a[j] = fmaf(wv.y, av[c4 + 1], a[j]);
        a[j] = fmaf(wv.z, av[c4 + 2], a[j]);
        a[j] = fmaf(wv.w, av[c4 + 3], a[j]);
      }
    }
#pragma unroll
    for (int j = 0; j < 8; j++) {
      const size_t oi = ((size_t)(b * 64 + obase + o8 + j)) * NN + n;
      out[oi] = a[j] + x[oi];   // coalesced read+write
    }
  }
}

extern "C" void kernel_launch(void* const* d_in, const int* in_sizes, int n_in,
                              void* d_out, int out_size, void* d_ws, size_t ws_size,
                              hipStream_t stream) {
  const float* x     = (const float*)d_in[0];
  const float* wqkv  = (const float*)d_in[1];
  const float* bqkv  = (const float*)d_in[2];
  const float* wproj = (const float*)d_in[3];
  const float* bproj = (const float*)d_in[4];
  float* out = (float*)d_out;

  char* ws = (char*)d_ws;
  __bf16* Q = (__bf16*)(ws);                    // 2 MB
  __bf16* K = (__bf16*)(ws + (2u << 20));       // 2 MB
  __bf16* V = (__bf16*)(ws + (4u << 20));       // 2 MB
  float*  AO = (float*)(ws + (6u << 20));       // 4 MB

  qkv_kernel<<<dim3(16, NB, 6), 256, 0, stream>>>(x, wqkv, bqkv, Q, K, V);
  flash_kernel<<<dim3(64, NB), 256, 0, stream>>>(Q, K, V, AO);
  proj_kernel<<<dim3(16, NB, 2), 256, 0, stream>>>(AO, wproj, bproj, x, out);
}

// Round 3
// 145.723 us; speedup vs baseline: 1.4599x; 1.4599x over previous
//
#include <hip/hip_runtime.h>

typedef __bf16 bf16x8 __attribute__((ext_vector_type(8)));
typedef float f32x4 __attribute__((ext_vector_type(4)));

#define NB 4
#define NC 64
#define NN 4096
#define SPLIT 4   // key-dim splits for flash (occupancy)

// ---------------------------------------------------------------------------
// Kernel 1: QKV projection.  x:[B,C,N] fp32, w_qkv:[3C,C], b_qkv:[3C]
// Outputs: Q,K as bf16 [B,N,C] ; V as bf16 [B,C,N]
// grid(16, B, 24): z -> {q,k,v} x 8-output group.  1536 blocks.
// ---------------------------------------------------------------------------
__global__ __launch_bounds__(256) void qkv_kernel(
    const float* __restrict__ x, const float* __restrict__ wqkv,
    const float* __restrict__ bqkv,
    __bf16* __restrict__ Qg, __bf16* __restrict__ Kg, __bf16* __restrict__ Vg)
{
  const int b = blockIdx.y;
  const int z = blockIdx.z;
  const int tsel = z >> 3;           // 0=q, 1=k, 2=v
  const int obase = (z & 7) * 8;     // which 8 output channels
  const int n = blockIdx.x * 256 + threadIdx.x;

  __shared__ float wsh[8 * 64];      // 512 floats, 256 threads -> 2 each
  __shared__ float bsh[8];
  wsh[threadIdx.x]       = wqkv[(tsel * 64 + obase) * 64 + threadIdx.x];
  wsh[threadIdx.x + 256] = wqkv[(tsel * 64 + obase) * 64 + threadIdx.x + 256];
  if (threadIdx.x < 8) bsh[threadIdx.x] = bqkv[tsel * 64 + obase + threadIdx.x];
  __syncthreads();

  float xv[64];
#pragma unroll
  for (int c = 0; c < 64; c++)
    xv[c] = x[((size_t)(b * 64 + c)) * NN + n];   // coalesced across lanes

  float a[8];
#pragma unroll
  for (int j = 0; j < 8; j++) a[j] = bsh[j];
#pragma unroll
  for (int c4 = 0; c4 < 64; c4 += 4) {
#pragma unroll
    for (int j = 0; j < 8; j++) {
      const float4 wv = *(const float4*)&wsh[j * 64 + c4];
      a[j] = fmaf(wv.x, xv[c4 + 0], a[j]);
      a[j] = fmaf(wv.y, xv[c4 + 1], a[j]);
      a[j] = fmaf(wv.z, xv[c4 + 2], a[j]);
      a[j] = fmaf(wv.w, xv[c4 + 3], a[j]);
    }
  }
  if (tsel == 2) {
#pragma unroll
    for (int j = 0; j < 8; j++)
      Vg[((size_t)(b * 64 + obase + j)) * NN + n] = (__bf16)a[j];  // coalesced
  } else {
    bf16x8 pk;
#pragma unroll
    for (int j = 0; j < 8; j++) pk[j] = (__bf16)a[j];
    __bf16* base = (tsel == 0 ? Qg : Kg);
    *(bf16x8*)(base + ((size_t)(b * NN + n)) * 64 + obase) = pk;
  }
}

// ---------------------------------------------------------------------------
// Kernel 2: flash attention, split-K.  Q,K:[B,N,C] bf16, V:[B,C,N] bf16
// -> Opart:[S,B,N,C] bf16 (unnormalized), ml:[S,B,N] float2 (m, l)
// grid(64, B, SPLIT), 256 threads = 4 waves; each wave owns 16 queries,
// each z-split handles NN/SPLIT keys.  Online softmax in log2 domain.
// l kept per-lane (this lane's 4 columns); reduced once in epilogue.
// ---------------------------------------------------------------------------
__global__ __launch_bounds__(256) void flash_kernel(
    const __bf16* __restrict__ Q, const __bf16* __restrict__ K,
    const __bf16* __restrict__ V, __bf16* __restrict__ Opart,
    float2* __restrict__ ml)
{
  const int b = blockIdx.y;
  const int s = blockIdx.z;
  const int tid = threadIdx.x;
  const int wave = tid >> 6;
  const int lane = tid & 63;
  const int quad = lane >> 4;
  const int l16 = lane & 15;

  __shared__ __bf16 Kt[64 * 72];      // [key][c], padded
  __shared__ __bf16 Vt[64 * 72];      // [c][key], padded
  __shared__ __bf16 Pt[4][16 * 72];   // per-wave P scratch [q][key], padded

  const int q0 = blockIdx.x * 64 + wave * 16;

  // Q fragments: A[m=l16][k=quad*8+j] for c 0..31 and 32..63
  const __bf16* qrow = Q + ((size_t)(b * NN + q0 + l16)) * 64;
  const bf16x8 qf0 = *(const bf16x8*)(qrow + quad * 8);
  const bf16x8 qf1 = *(const bf16x8*)(qrow + 32 + quad * 8);

  f32x4 acc[4];     // O accumulator; row=quad*4+r, col=ct*16+l16
#pragma unroll
  for (int ct = 0; ct < 4; ct++) acc[ct] = (f32x4){0.f, 0.f, 0.f, 0.f};
  float m[4], l[4];
#pragma unroll
  for (int r = 0; r < 4; r++) { m[r] = -1e30f; l[r] = 0.f; }

  const float sc = 0.125f * 1.44269504088896340736f;  // 1/sqrt(C) * log2(e)

  const int kbeg = s * (NN / SPLIT);
  const int kend = kbeg + (NN / SPLIT);
  for (int kt0 = kbeg; kt0 < kend; kt0 += 64) {
    __syncthreads();
#pragma unroll
    for (int it = 0; it < 2; it++) {
      const int chunk = tid + it * 256;          // 512 chunks of 8 bf16
      const int row = chunk >> 3, col8 = (chunk & 7) * 8;
      *(bf16x8*)(&Kt[row * 72 + col8]) =
          *(const bf16x8*)(K + ((size_t)(b * NN + kt0 + row)) * 64 + col8);
      *(bf16x8*)(&Vt[row * 72 + col8]) =
          *(const bf16x8*)(V + ((size_t)(b * 64 + row)) * NN + kt0 + col8);
    }
    __syncthreads();

    // S = Q K^T for 4 key tiles of 16
    f32x4 sv[4];
#pragma unroll
    for (int t = 0; t < 4; t++) {
      const bf16x8 kf0 = *(const bf16x8*)(&Kt[(t * 16 + l16) * 72 + quad * 8]);
      const bf16x8 kf1 = *(const bf16x8*)(&Kt[(t * 16 + l16) * 72 + 32 + quad * 8]);
      f32x4 z = (f32x4){0.f, 0.f, 0.f, 0.f};
      z = __builtin_amdgcn_mfma_f32_16x16x32_bf16(qf0, kf0, z, 0, 0, 0);
      z = __builtin_amdgcn_mfma_f32_16x16x32_bf16(qf1, kf1, z, 0, 0, 0);
      sv[t] = z;
    }

    // online softmax per row r (row = quad*4+r, cols over 16 lanes)
    float alpha[4];
#pragma unroll
    for (int r = 0; r < 4; r++) {
      float s0 = sv[0][r] * sc, s1 = sv[1][r] * sc, s2 = sv[2][r] * sc, s3 = sv[3][r] * sc;
      float mx = fmaxf(fmaxf(s0, s1), fmaxf(s2, s3));
      mx = fmaxf(mx, __shfl_xor(mx, 1));
      mx = fmaxf(mx, __shfl_xor(mx, 2));
      mx = fmaxf(mx, __shfl_xor(mx, 4));
      mx = fmaxf(mx, __shfl_xor(mx, 8));
      const float mnew = fmaxf(m[r], mx);
      alpha[r] = exp2f(m[r] - mnew);
      m[r] = mnew;
      const float p0 = exp2f(s0 - mnew), p1 = exp2f(s1 - mnew);
      const float p2 = exp2f(s2 - mnew), p3 = exp2f(s3 - mnew);
      l[r] = l[r] * alpha[r] + ((p0 + p1) + (p2 + p3));   // per-lane partial
      Pt[wave][(quad * 4 + r) * 72 + 0 * 16 + l16] = (__bf16)p0;
      Pt[wave][(quad * 4 + r) * 72 + 1 * 16 + l16] = (__bf16)p1;
      Pt[wave][(quad * 4 + r) * 72 + 2 * 16 + l16] = (__bf16)p2;
      Pt[wave][(quad * 4 + r) * 72 + 3 * 16 + l16] = (__bf16)p3;
    }

#pragma unroll
    for (int ct = 0; ct < 4; ct++)
#pragma unroll
      for (int r = 0; r < 4; r++) acc[ct][r] *= alpha[r];

    // O += P V
#pragma unroll
    for (int kb = 0; kb < 2; kb++) {
      const bf16x8 pf = *(const bf16x8*)(&Pt[wave][l16 * 72 + kb * 32 + quad * 8]);
#pragma unroll
      for (int ct = 0; ct < 4; ct++) {
        const bf16x8 vf = *(const bf16x8*)(&Vt[(ct * 16 + l16) * 72 + kb * 32 + quad * 8]);
        acc[ct] = __builtin_amdgcn_mfma_f32_16x16x32_bf16(pf, vf, acc[ct], 0, 0, 0);
      }
    }
  }

  // epilogue: reduce l across the 16 row-lanes, store unnormalized partials
#pragma unroll
  for (int r = 0; r < 4; r++) {
    float lr = l[r];
    lr += __shfl_xor(lr, 1);
    lr += __shfl_xor(lr, 2);
    lr += __shfl_xor(lr, 4);
    lr += __shfl_xor(lr, 8);
    l[r] = lr;
  }
#pragma unroll
  for (int ct = 0; ct < 4; ct++)
#pragma unroll
    for (int r = 0; r < 4; r++)
      Opart[(((size_t)((s * NB + b)) * NN) + q0 + quad * 4 + r) * 64 + ct * 16 + l16] =
          (__bf16)acc[ct][r];
  if (l16 == 0) {
#pragma unroll
    for (int r = 0; r < 4; r++)
      ml[((size_t)(s * NB + b)) * NN + q0 + quad * 4 + r] = make_float2(m[r], l[r]);
  }
}

// ---------------------------------------------------------------------------
// Kernel 2b: combine split-K partials -> AO:[B,N,C] fp32
// grid(B*N*C/256), thread <-> (b,n,c), c = lane-contiguous (coalesced).
// ---------------------------------------------------------------------------
__global__ __launch_bounds__(256) void combine_kernel(
    const __bf16* __restrict__ Opart, const float2* __restrict__ ml,
    float* __restrict__ AO)
{
  const int idx = blockIdx.x * 256 + threadIdx.x;   // < B*N*C = 2^20
  const int c = idx & 63;
  const int q = (idx >> 6) & (NN - 1);
  const int b = idx >> 18;

  float2 t[SPLIT];
#pragma unroll
  for (int s = 0; s < SPLIT; s++) t[s] = ml[((size_t)(s * NB + b)) * NN + q];
  float M = t[0].x;
#pragma unroll
  for (int s = 1; s < SPLIT; s++) M = fmaxf(M, t[s].x);
  float L = 0.f, acc = 0.f;
#pragma unroll
  for (int s = 0; s < SPLIT; s++) {
    const float w = exp2f(t[s].x - M);
    L += w * t[s].y;
    acc += w * (float)Opart[(((size_t)(s * NB + b)) * NN + q) * 64 + c];
  }
  AO[((size_t)(b * NN + q)) * 64 + c] = acc / L;
}

// ---------------------------------------------------------------------------
// Kernel 3: output projection + bias + residual (fp32).
// grid(16, B, 8): z selects 8 output channels.  512 blocks.
// ---------------------------------------------------------------------------
__global__ __launch_bounds__(256) void proj_kernel(
    const float* __restrict__ AO, const float* __restrict__ wproj,
    const float* __restrict__ bproj, const float* __restrict__ x,
    float* __restrict__ out)
{
  const int b = blockIdx.y;
  const int obase = blockIdx.z * 8;
  const int n = blockIdx.x * 256 + threadIdx.x;

  __shared__ float wsh[8 * 64];      // 512 floats, 256 threads -> 2 each
  __shared__ float bsh[8];
  wsh[threadIdx.x]       = wproj[obase * 64 + threadIdx.x];
  wsh[threadIdx.x + 256] = wproj[obase * 64 + threadIdx.x + 256];
  if (threadIdx.x < 8) bsh[threadIdx.x] = bproj[obase + threadIdx.x];
  __syncthreads();

  float av[64];
#pragma unroll
  for (int c4 = 0; c4 < 64; c4 += 4) {
    const float4 v = *(const float4*)&AO[((size_t)(b * NN + n)) * 64 + c4];
    av[c4] = v.x; av[c4 + 1] = v.y; av[c4 + 2] = v.z; av[c4 + 3] = v.w;
  }

  float a[8];
#pragma unroll
  for (int j = 0; j < 8; j++) a[j] = bsh[j];
#pragma unroll
  for (int c4 = 0; c4 < 64; c4 += 4) {
#pragma unroll
    for (int j = 0; j < 8; j++) {
      const float4 wv = *(const float4*)&wsh[j * 64 + c4];
      a[j] = fmaf(wv.x, av[c4 + 0], a[j]);
      a[j] = fmaf(wv.y, av[c4 + 1], a[j]);
      a[j] = fmaf(wv.z, av[c4 + 2], a[j]);
      a[j] = fmaf(wv.w, av[c4 + 3], a[j]);
    }
  }
#pragma unroll
  for (int j = 0; j < 8; j++) {
    const size_t oi = ((size_t)(b * 64 + obase + j)) * NN + n;
    out[oi] = a[j] + x[oi];   // coalesced read+write
  }
}

extern "C" void kernel_launch(void* const* d_in, const int* in_sizes, int n_in,
                              void* d_out, int out_size, void* d_ws, size_t ws_size,
                              hipStream_t stream) {
  const float* x     = (const float*)d_in[0];
  const float* wqkv  = (const float*)d_in[1];
  const float* bqkv  = (const float*)d_in[2];
  const float* wproj = (const float*)d_in[3];
  const float* bproj = (const float*)d_in[4];
  float* out = (float*)d_out;

  // Workspace layout (14.5 MB total).  AO reuses the Q/K region: Q,K are
  // dead once flash_kernel completes, and combine (writer of AO) is
  // stream-ordered after flash.
  char* ws = (char*)d_ws;
  __bf16* Q     = (__bf16*)(ws);                  // [0,  2 MB)
  __bf16* K     = (__bf16*)(ws + (2u << 20));     // [2,  4 MB)
  __bf16* V     = (__bf16*)(ws + (4u << 20));     // [4,  6 MB)
  __bf16* Opart = (__bf16*)(ws + (6u << 20));     // [6, 14 MB)
  float2* ml    = (float2*)(ws + (14u << 20));    // [14, 14.5 MB)
  float*  AO    = (float*)(ws);                   // [0,  4 MB) reuse

  qkv_kernel<<<dim3(16, NB, 24), 256, 0, stream>>>(x, wqkv, bqkv, Q, K, V);
  flash_kernel<<<dim3(64, NB, SPLIT), 256, 0, stream>>>(Q, K, V, Opart, ml);
  combine_kernel<<<dim3((NB * NN * NC) / 256), 256, 0, stream>>>(Opart, ml, AO);
  proj_kernel<<<dim3(16, NB, 8), 256, 0, stream>>>(AO, wproj, bproj, x, out);
}